// Round 2
// baseline (789.878 us; speedup 1.0000x reference)
//
#include <hip/hip_runtime.h>
#include <hip/hip_bf16.h>

// CRF forward + gold score via MFMA.
// B=4096, L=1024, T=32. One wave per 16 sequences; lane = (batch n=lane&15, q=lane>>4).
// Per step: acc[b,s] = sum_prev Mexp[s][prev] * E[prev,b] via 2x mfma_f32_16x16x32_bf16
// with ROW-PERMUTED A so that the D layout (lane holds states 8q..8q+7 for batch n)
// is exactly the B-fragment layout of the next step -> no cross-lane E movement.
//
// Scaling scheme (amortized renorm):
//   per step:   E_new = (Mexp . E) * exp(f - ln64)          (constant 2^-6 scale,
//                                                            drift stays in f32/bf16
//                                                            exponent range for >=8 steps)
//   per 8 steps: exact renorm by rcp(c1[0]) folded into the NEXT step's e,
//                so shfl+rcp run concurrent with the next mfma, never in front of it.
//   alpha = mAcc(sum of log(c[0]) at renorms) + 1024*ln64 + log(sum E*expStop)
//
// e is software-pipelined one step ahead (computed from ring slot l+1 during step l),
// so the serial chain is just mfma -> mul -> cvt -> mfma.
// Prefetch ring is statically indexed (outer x127, inner fully-unrolled x8) -> VGPRs.

#define BATCH 4096
#define LSEQ  1024
#define T     32
#define START 30
#define STOP  31

#define LN64 4.158883083f        /* 6*ln2 : per-step constant scale 2^-6 */
#define SUM_LN64 4258.6963f      /* 1024 * LN64 */

typedef __attribute__((ext_vector_type(8))) short short8;
typedef __attribute__((ext_vector_type(4))) float f32x4;

static __device__ __forceinline__ short bf16b(float x) {
    union { __hip_bfloat16 h; short s; } u;
    u.h = __float2bfloat16(x);
    return u.s;
}

__global__ __launch_bounds__(64) void crf_fwd_mfma(
    const float* __restrict__ feats,   // [B, L, T]
    const float* __restrict__ trans,   // [T, T] (next, prev)
    const int*   __restrict__ tags,    // [B, L]
    float*       __restrict__ out)     // [B]
{
    __shared__ float trans_s[T * T];
    const int lane = threadIdx.x;      // 0..63
    for (int i = lane; i < T * T; i += 64) trans_s[i] = trans[i];
    __syncthreads();

    const int n = lane & 15;           // batch within the wave's group of 16
    const int q = lane >> 4;           // quadrant: owns states 8q..8q+7
    const int b = blockIdx.x * 16 + n;

    // A fragments (Mexp, row-permuted). A[m][k]: m = lane&15, k = 8q + j.
    // A1 row m -> state 8*(m>>2)+(m&3); A2 row m -> that +4. exp(-10000)==0 exact.
    short8 a1, a2;
    {
        const int s1 = 8 * (n >> 2) + (n & 3);
        const int s2 = s1 + 4;
#pragma unroll
        for (int j = 0; j < 8; ++j) {
            a1[j] = bf16b(__expf(trans_s[s1 * T + 8 * q + j]));
            a2[j] = bf16b(__expf(trans_s[s2 * T + 8 * q + j]));
        }
    }

    // B fragment: E[k = 8q+j][n]. Init fv: START=0, rest -1e4 -> E = one-hot(START).
    short8 bfrag;
#pragma unroll
    for (int j = 0; j < 8; ++j) bfrag[j] = 0;
    if (q == 3) bfrag[6] = bf16b(1.0f);          // state 30 = 8*3+6

    const f32x4* fp = (const f32x4*)(feats + (size_t)b * (LSEQ * T) + 8 * q);
    const int*   tb = tags + (size_t)b * LSEQ;

    // 8-deep register ring: 2 float4 (states 8q..8q+7) + tag per step.
    // All indices below are compile-time constants -> stays in VGPRs.
    f32x4 fr0[8], fr1[8];
    int   tbuf[8];
#pragma unroll
    for (int i = 0; i < 8; ++i) {
        fr0[i] = fp[i * 8];
        fr1[i] = fp[i * 8 + 1];
        tbuf[i] = tb[i];
    }

    float mAcc = 0.0f;        // sum of log(c[0]) at the per-8-step renorms
    float gold_trans = 0.0f;  // uniform across q
    float gold_emit  = 0.0f;  // per-lane partial, reduced at end
    int   prev_tag = START;
    float ev[8];              // fp32 E of the current step (kept for epilogue)
    float eCur[8];            // e for the CURRENT step (pipelined 1 ahead)

    // prologue: e for step 0 (no renorm factor yet)
    {
        const f32x4 g0 = fr0[0];
        const f32x4 g1 = fr1[0];
#pragma unroll
        for (int r = 0; r < 4; ++r) {
            eCur[r]     = __expf(g0[r] - LN64);
            eCur[4 + r] = __expf(g1[r] - LN64);
        }
    }

    const f32x4 zacc = {0.f, 0.f, 0.f, 0.f};

#define CRF_STEP(l, slot, DO_PF, DO_NEXT, DO_RENORM)                           \
    {                                                                          \
        const f32x4 f0  = fr0[slot];                                           \
        const f32x4 f1  = fr1[slot];                                           \
        const int   tag = tbuf[slot];                                          \
        if (DO_PF) {                                                           \
            fr0[slot]  = fp[((l) + 8) * 8];                                    \
            fr1[slot]  = fp[((l) + 8) * 8 + 1];                                \
            tbuf[slot] = tb[(l) + 8];                                          \
        }                                                                      \
        f32x4 c1 = __builtin_amdgcn_mfma_f32_16x16x32_bf16(a1, bfrag, zacc, 0, 0, 0); \
        f32x4 c2 = __builtin_amdgcn_mfma_f32_16x16x32_bf16(a2, bfrag, zacc, 0, 0, 0); \
        _Pragma("unroll")                                                      \
        for (int r = 0; r < 4; ++r) {                                          \
            ev[r]     = c1[r] * eCur[r];                                       \
            ev[4 + r] = c2[r] * eCur[4 + r];                                   \
        }                                                                      \
        _Pragma("unroll")                                                      \
        for (int j = 0; j < 8; ++j) bfrag[j] = bf16b(ev[j]);                   \
        /* gold: transitions (uniform) + emission (owned by lane q==tag>>3) */ \
        gold_trans += trans_s[tag * T + prev_tag];                             \
        {                                                                      \
            const f32x4 fs  = (tag & 4) ? f1 : f0;                             \
            const float p01 = (tag & 1) ? fs[1] : fs[0];                       \
            const float p23 = (tag & 1) ? fs[3] : fs[2];                       \
            const float pk  = (tag & 2) ? p23 : p01;                           \
            if ((tag >> 3) == q) gold_emit += pk;                              \
        }                                                                      \
        prev_tag = tag;                                                        \
        if (DO_NEXT) { /* pipeline e for step l+1 from ring slot (slot+1)&7 */ \
            const int   ns = ((slot) + 1) & 7;                                 \
            const f32x4 g0 = fr0[ns];                                          \
            const f32x4 g1 = fr1[ns];                                          \
            _Pragma("unroll")                                                  \
            for (int r = 0; r < 4; ++r) {                                      \
                eCur[r]     = __expf(g0[r] - LN64);                            \
                eCur[4 + r] = __expf(g1[r] - LN64);                            \
            }                                                                  \
        }                                                                      \
        if (DO_RENORM) { /* exact renorm, folded into next step's e */         \
            const float cb = __shfl(c1[0], n, 64); /* state 0, batch n */      \
            const float iv = __builtin_amdgcn_rcpf(cb);                        \
            mAcc += __logf(cb);                                                \
            _Pragma("unroll")                                                  \
            for (int j = 0; j < 8; ++j) eCur[j] *= iv;                         \
        }                                                                      \
    }

    // main loop: outer x127, inner fully unrolled x8 so slot is constant.
    // Renorm computed at slot 7, applied (via eCur) at the next slot-0 step.
    for (int lo = 0; lo < LSEQ - 8; lo += 8) {
        CRF_STEP(lo + 0, 0, 1, 1, 0)
        CRF_STEP(lo + 1, 1, 1, 1, 0)
        CRF_STEP(lo + 2, 2, 1, 1, 0)
        CRF_STEP(lo + 3, 3, 1, 1, 0)
        CRF_STEP(lo + 4, 4, 1, 1, 0)
        CRF_STEP(lo + 5, 5, 1, 1, 0)
        CRF_STEP(lo + 6, 6, 1, 1, 0)
        CRF_STEP(lo + 7, 7, 1, 1, 1)
    }
    // epilogue: last 8 steps, no prefetch, no renorm; last step computes no eNext
    CRF_STEP(LSEQ - 8, 0, 0, 1, 0)
    CRF_STEP(LSEQ - 7, 1, 0, 1, 0)
    CRF_STEP(LSEQ - 6, 2, 0, 1, 0)
    CRF_STEP(LSEQ - 5, 3, 0, 1, 0)
    CRF_STEP(LSEQ - 4, 4, 0, 1, 0)
    CRF_STEP(LSEQ - 3, 5, 0, 1, 0)
    CRF_STEP(LSEQ - 2, 6, 0, 1, 0)
    CRF_STEP(LSEQ - 1, 7, 0, 0, 0)
#undef CRF_STEP

    // alpha = mAcc + 1024*ln64 + log(sum_s E[s] * Mexp[STOP][s])
    // (ev carries the residual drift since the last renorm; that's fine in f32)
    float s = 0.0f;
#pragma unroll
    for (int j = 0; j < 8; ++j)
        s += ev[j] * __expf(trans_s[STOP * T + 8 * q + j]);
    s += __shfl_xor(s, 16, 64);
    s += __shfl_xor(s, 32, 64);
    const float alpha = mAcc + SUM_LN64 + __logf(s);

    float ge = gold_emit;
    ge += __shfl_xor(ge, 16, 64);
    ge += __shfl_xor(ge, 32, 64);
    const float gold = ge + gold_trans + trans_s[STOP * T + prev_tag];

    if (lane < 16) out[b] = alpha - gold;
}

extern "C" void kernel_launch(void* const* d_in, const int* in_sizes, int n_in,
                              void* d_out, int out_size, void* d_ws, size_t ws_size,
                              hipStream_t stream) {
    const float* feats = (const float*)d_in[0];
    const float* trans = (const float*)d_in[1];
    const int*   tags  = (const int*)d_in[2];
    float*       out   = (float*)d_out;

    // 16 sequences per 64-thread block -> 256 blocks = 1 wave per CU
    crf_fwd_mfma<<<BATCH / 16, 64, 0, stream>>>(feats, trans, tags, out);
}

// Round 3
// 763.014 us; speedup vs baseline: 1.0352x; 1.0352x over previous
//
#include <hip/hip_runtime.h>
#include <hip/hip_bf16.h>

// CRF forward + gold score via MFMA.
// B=4096, L=1024, T=32. One wave per 16 sequences; lane = (batch n=lane&15, q=lane>>4).
// Per step: acc[b,s] = sum_prev Mexp[s][prev] * E[prev,b] via 2x mfma_f32_16x16x32_bf16
// with ROW-PERMUTED A so that the D layout (lane holds states 8q..8q+7 for batch n)
// is exactly the B-fragment layout of the next step -> no cross-lane E movement.
//
// Scaling: per step constant 2^-6 folded into e = exp(f - ln64); exact renorm by
// rcp(c1[0]) every 8 steps, folded into the NEXT step's e (off the serial chain).
// alpha = mAcc + 1024*ln64 + log(sum E*expStop).
//
// This round:
//  - Prefetch ring deepened 8 -> 16 (statically indexed -> VGPRs). At 1 wave/CU
//    the ring depth IS the memory concurrency (Little's law): 8-deep = 4.7 MB
//    in flight device-wide, right at the BW*latency cliff; 16-deep = 9.4 MB.
//  - gold_trans (and the STOP transition) moved to a tiny second kernel over
//    tags only -> removes a serial ds_read + lgkmcnt + adds from every step.

#define BATCH 4096
#define LSEQ  1024
#define T     32
#define START 30
#define STOP  31

#define LN64 4.158883083f        /* 6*ln2 : per-step constant scale 2^-6 */
#define SUM_LN64 4258.6963f      /* 1024 * LN64 */

typedef __attribute__((ext_vector_type(8))) short short8;
typedef __attribute__((ext_vector_type(4))) float f32x4;
typedef __attribute__((ext_vector_type(4))) int   i32x4;

static __device__ __forceinline__ short bf16b(float x) {
    union { __hip_bfloat16 h; short s; } u;
    u.h = __float2bfloat16(x);
    return u.s;
}

__global__ __launch_bounds__(64, 1) void crf_fwd_mfma(
    const float* __restrict__ feats,   // [B, L, T]
    const float* __restrict__ trans,   // [T, T] (next, prev)
    const int*   __restrict__ tags,    // [B, L]
    float*       __restrict__ out)     // [B]
{
    __shared__ float trans_s[T * T];
    const int lane = threadIdx.x;      // 0..63
    for (int i = lane; i < T * T; i += 64) trans_s[i] = trans[i];
    __syncthreads();

    const int n = lane & 15;           // batch within the wave's group of 16
    const int q = lane >> 4;           // quadrant: owns states 8q..8q+7
    const int b = blockIdx.x * 16 + n;

    // A fragments (Mexp, row-permuted). A[m][k]: m = lane&15, k = 8q + j.
    // A1 row m -> state 8*(m>>2)+(m&3); A2 row m -> that +4. exp(-10000)==0 exact.
    short8 a1, a2;
    {
        const int s1 = 8 * (n >> 2) + (n & 3);
        const int s2 = s1 + 4;
#pragma unroll
        for (int j = 0; j < 8; ++j) {
            a1[j] = bf16b(__expf(trans_s[s1 * T + 8 * q + j]));
            a2[j] = bf16b(__expf(trans_s[s2 * T + 8 * q + j]));
        }
    }

    // B fragment: E[k = 8q+j][n]. Init fv: START=0, rest -1e4 -> E = one-hot(START).
    short8 bfrag;
#pragma unroll
    for (int j = 0; j < 8; ++j) bfrag[j] = 0;
    if (q == 3) bfrag[6] = bf16b(1.0f);          // state 30 = 8*3+6

    const f32x4* fp = (const f32x4*)(feats + (size_t)b * (LSEQ * T) + 8 * q);
    const int*   tb = tags + (size_t)b * LSEQ;

    // 16-deep register ring: 2 float4 (states 8q..8q+7) + tag per step.
    // All indices below are compile-time constants -> stays in VGPRs.
    f32x4 fr0[16], fr1[16];
    int   tbuf[16];
#pragma unroll
    for (int i = 0; i < 16; ++i) {
        fr0[i] = fp[i * 8];
        fr1[i] = fp[i * 8 + 1];
        tbuf[i] = tb[i];
    }

    float mAcc = 0.0f;        // sum of log(c[0]) at the per-8-step renorms
    float gold_emit = 0.0f;   // per-lane partial, reduced at end
    float ev[8];              // fp32 E of the current step (kept for epilogue)
    float eCur[8];            // e for the CURRENT step (pipelined 1 ahead)

    // prologue: e for step 0 (no renorm factor yet)
    {
        const f32x4 g0 = fr0[0];
        const f32x4 g1 = fr1[0];
#pragma unroll
        for (int r = 0; r < 4; ++r) {
            eCur[r]     = __expf(g0[r] - LN64);
            eCur[4 + r] = __expf(g1[r] - LN64);
        }
    }

    const f32x4 zacc = {0.f, 0.f, 0.f, 0.f};

#define CRF_STEP(l, slot, DO_PF, DO_NEXT, DO_RENORM)                           \
    {                                                                          \
        const f32x4 f0  = fr0[slot];                                           \
        const f32x4 f1  = fr1[slot];                                           \
        const int   tag = tbuf[slot];                                          \
        if (DO_PF) {                                                           \
            fr0[slot]  = fp[((l) + 16) * 8];                                   \
            fr1[slot]  = fp[((l) + 16) * 8 + 1];                               \
            tbuf[slot] = tb[(l) + 16];                                         \
        }                                                                      \
        f32x4 c1 = __builtin_amdgcn_mfma_f32_16x16x32_bf16(a1, bfrag, zacc, 0, 0, 0); \
        f32x4 c2 = __builtin_amdgcn_mfma_f32_16x16x32_bf16(a2, bfrag, zacc, 0, 0, 0); \
        _Pragma("unroll")                                                      \
        for (int r = 0; r < 4; ++r) {                                          \
            ev[r]     = c1[r] * eCur[r];                                       \
            ev[4 + r] = c2[r] * eCur[4 + r];                                   \
        }                                                                      \
        _Pragma("unroll")                                                      \
        for (int j = 0; j < 8; ++j) bfrag[j] = bf16b(ev[j]);                   \
        /* gold emission: owned by lane with q == tag>>3 */                    \
        {                                                                      \
            const f32x4 fs  = (tag & 4) ? f1 : f0;                             \
            const float p01 = (tag & 1) ? fs[1] : fs[0];                       \
            const float p23 = (tag & 1) ? fs[3] : fs[2];                       \
            const float pk  = (tag & 2) ? p23 : p01;                           \
            if ((tag >> 3) == q) gold_emit += pk;                              \
        }                                                                      \
        if (DO_NEXT) { /* pipeline e for step l+1 from ring slot (slot+1)&15 */\
            const int   ns = ((slot) + 1) & 15;                                \
            const f32x4 g0 = fr0[ns];                                          \
            const f32x4 g1 = fr1[ns];                                          \
            _Pragma("unroll")                                                  \
            for (int r = 0; r < 4; ++r) {                                      \
                eCur[r]     = __expf(g0[r] - LN64);                            \
                eCur[4 + r] = __expf(g1[r] - LN64);                            \
            }                                                                  \
        }                                                                      \
        if (DO_RENORM) { /* exact renorm, folded into next step's e */         \
            const float cb = __shfl(c1[0], n, 64); /* state 0, batch n */      \
            const float iv = __builtin_amdgcn_rcpf(cb);                        \
            mAcc += __logf(cb);                                                \
            _Pragma("unroll")                                                  \
            for (int j = 0; j < 8; ++j) eCur[j] *= iv;                         \
        }                                                                      \
    }

    // main loop: outer x63, inner fully unrolled x16 so slot is constant.
    // Renorm every 8 steps (slots 7 and 15), applied via eCur at the next step.
    for (int lo = 0; lo < LSEQ - 16; lo += 16) {
        CRF_STEP(lo + 0,  0,  1, 1, 0)
        CRF_STEP(lo + 1,  1,  1, 1, 0)
        CRF_STEP(lo + 2,  2,  1, 1, 0)
        CRF_STEP(lo + 3,  3,  1, 1, 0)
        CRF_STEP(lo + 4,  4,  1, 1, 0)
        CRF_STEP(lo + 5,  5,  1, 1, 0)
        CRF_STEP(lo + 6,  6,  1, 1, 0)
        CRF_STEP(lo + 7,  7,  1, 1, 1)
        CRF_STEP(lo + 8,  8,  1, 1, 0)
        CRF_STEP(lo + 9,  9,  1, 1, 0)
        CRF_STEP(lo + 10, 10, 1, 1, 0)
        CRF_STEP(lo + 11, 11, 1, 1, 0)
        CRF_STEP(lo + 12, 12, 1, 1, 0)
        CRF_STEP(lo + 13, 13, 1, 1, 0)
        CRF_STEP(lo + 14, 14, 1, 1, 0)
        CRF_STEP(lo + 15, 15, 1, 1, 1)
    }
    // epilogue: last 16 steps (l = 1008..1023), no prefetch, renorm at slot 7
    CRF_STEP(LSEQ - 16, 0,  0, 1, 0)
    CRF_STEP(LSEQ - 15, 1,  0, 1, 0)
    CRF_STEP(LSEQ - 14, 2,  0, 1, 0)
    CRF_STEP(LSEQ - 13, 3,  0, 1, 0)
    CRF_STEP(LSEQ - 12, 4,  0, 1, 0)
    CRF_STEP(LSEQ - 11, 5,  0, 1, 0)
    CRF_STEP(LSEQ - 10, 6,  0, 1, 0)
    CRF_STEP(LSEQ - 9,  7,  0, 1, 1)
    CRF_STEP(LSEQ - 8,  8,  0, 1, 0)
    CRF_STEP(LSEQ - 7,  9,  0, 1, 0)
    CRF_STEP(LSEQ - 6,  10, 0, 1, 0)
    CRF_STEP(LSEQ - 5,  11, 0, 1, 0)
    CRF_STEP(LSEQ - 4,  12, 0, 1, 0)
    CRF_STEP(LSEQ - 3,  13, 0, 1, 0)
    CRF_STEP(LSEQ - 2,  14, 0, 1, 0)
    CRF_STEP(LSEQ - 1,  15, 0, 0, 0)
#undef CRF_STEP

    // alpha = mAcc + 1024*ln64 + log(sum_s E[s] * Mexp[STOP][s])
    // (ev carries the residual drift since the last renorm; that's fine in f32)
    float s = 0.0f;
#pragma unroll
    for (int j = 0; j < 8; ++j)
        s += ev[j] * __expf(trans_s[STOP * T + 8 * q + j]);
    s += __shfl_xor(s, 16, 64);
    s += __shfl_xor(s, 32, 64);
    const float alpha = mAcc + SUM_LN64 + __logf(s);

    float ge = gold_emit;
    ge += __shfl_xor(ge, 16, 64);
    ge += __shfl_xor(ge, 32, 64);

    // gold transition score is applied by crf_gold_trans (second kernel).
    if (lane < 16) out[b] = alpha - ge;
}

// Subtract the gold transition score: sum_l trans[tag_l, tag_{l-1}] (tag_{-1}=START)
// plus trans[STOP, tag_{L-1}]. Pure tags+trans -> cheap, memory-coalesced.
__global__ __launch_bounds__(64) void crf_gold_trans(
    const float* __restrict__ trans,   // [T, T]
    const int*   __restrict__ tags,    // [B, L]
    float*       __restrict__ out)     // [B] (already holds alpha - emit score)
{
    __shared__ float trans_s[T * T];
    const int lane = threadIdx.x;
    for (int i = lane; i < T * T; i += 64) trans_s[i] = trans[i];
    __syncthreads();

    const int b = blockIdx.x;
    const int* tb = tags + (size_t)b * LSEQ;

    // lane handles steps lane*16 .. lane*16+15
    const i32x4* tp = (const i32x4*)(tb + lane * 16);
    int tg[16];
#pragma unroll
    for (int v = 0; v < 4; ++v) {
        const i32x4 t = tp[v];
#pragma unroll
        for (int j = 0; j < 4; ++j) tg[v * 4 + j] = t[j];
    }

    // prev tag for this lane's first step = previous lane's last tag (START for lane 0)
    const int fromPrevLane = __shfl_up(tg[15], 1, 64);
    int prev = (lane == 0) ? START : fromPrevLane;

    float acc = 0.0f;
#pragma unroll
    for (int i = 0; i < 16; ++i) {
        acc += trans_s[tg[i] * T + prev];
        prev = tg[i];
    }

    acc += __shfl_xor(acc, 1, 64);
    acc += __shfl_xor(acc, 2, 64);
    acc += __shfl_xor(acc, 4, 64);
    acc += __shfl_xor(acc, 8, 64);
    acc += __shfl_xor(acc, 16, 64);
    acc += __shfl_xor(acc, 32, 64);

    const int lastTag = __shfl(tg[15], 63, 64);
    if (lane == 0) out[b] -= (acc + trans_s[STOP * T + lastTag]);
}

extern "C" void kernel_launch(void* const* d_in, const int* in_sizes, int n_in,
                              void* d_out, int out_size, void* d_ws, size_t ws_size,
                              hipStream_t stream) {
    const float* feats = (const float*)d_in[0];
    const float* trans = (const float*)d_in[1];
    const int*   tags  = (const int*)d_in[2];
    float*       out   = (float*)d_out;

    // 16 sequences per 64-thread block -> 256 blocks = 1 wave per CU
    crf_fwd_mfma<<<BATCH / 16, 64, 0, stream>>>(feats, trans, tags, out);
    // same stream -> ordered after the main kernel
    crf_gold_trans<<<BATCH, 64, 0, stream>>>(trans, tags, out);
}